// Round 12
// baseline (390.304 us; speedup 1.0000x reference)
//
#include <hip/hip_runtime.h>
#include <math.h>

typedef unsigned short u16;
typedef unsigned int   u32;
typedef float f32x4 __attribute__((ext_vector_type(4)));
typedef short bfx8  __attribute__((ext_vector_type(8)));

#define NB   2
#define CCH  128
#define HS   48
#define LL   2304        // 48*48
#define KW   2048        // 128*4*4
#define HO   96
#define PIX  9216        // 96*96
#define VHALF ((size_t)LL * KW)   // elements per split-K V buffer (9,437,184 B)

// Workspace layout. Peak address use 60,106,784 B < 60,198,912 B (r0-proven).
#define XTH_B 0                  // x2^T hi bf16 [2][2304][128] = 1,179,648
#define XTL_B 1179648            // x2^T lo bf16
#define PXN_B 2359296            // per-pixel sqnorm fp32 [2][2304]
#define NRM_B 2377728            // 1/norms fp32 [2][2304]
#define MM_B  2396160            // mm flags fp32 [2][2304]
#define WF_B  2414592            // fuse weights bf16 [64][9][128] = 147,456
#define WT_B  2562048            // W^T(compacted) bf16 = 9,437,184 -> ends 11,999,232
#define S_B   11999232           // S fp32 21,233,664 -> ends 33,232,896 (dead after zsumexp)
#define TBC_B S_B                // compacted Tbc bf16 10,616,832 -> ends 22,616,064 (aliases dead S head)
#define V_B   22616064           // V 3x9,437,184 = 28,311,552 -> ends 50,927,616
                                 //   overlaps dead S tail + dead Tbu (gemm2 runs after fixup). Serially safe.
#define TBU_B 33232896           // Tbu bf16 10,616,832 -> ends 43,849,728 (dead after fixup)
#define YT_B  54466560           // yT bf16 [2][9216][128] = 4,718,592 -> ends 59,185,152
#define CMAP_B 59185152          // int cmap [2][2304]
#define LIDX_B (CMAP_B + 18432)  // int lidx [2][2304]
#define MET_B  (LIDX_B + 18432)  // int meta [2][2]
#define STM_B  59222048          // statm fp32 [2304][48] = 442,368
#define STS_B  59664416          // stats fp32 [2304][48] = 442,368 -> ends 60,106,784

__device__ __forceinline__ u16 f2bf(float f) {      // round-to-nearest-even
    u32 u = __float_as_uint(f);
    u32 r = (u + 0x7fffu + ((u >> 16) & 1u)) >> 16;
    return (u16)r;
}
__device__ __forceinline__ float bf2f(u16 h) {
    return __uint_as_float(((u32)h) << 16);
}
__device__ __forceinline__ void gll16(const void* g, void* l) {
    __builtin_amdgcn_global_load_lds((const __attribute__((address_space(1))) void*)g,
                                     (__attribute__((address_space(3))) void*)l, 16, 0, 0);
}

// ---------------------------------------------------------------------------
__global__ __launch_bounds__(256) void xprep_k(const float* __restrict__ x2,
                                               u16* __restrict__ Xh, u16* __restrict__ Xl,
                                               float* __restrict__ pxn) {
    __shared__ float lt[32][130];
    int n = blockIdx.z;
    int pix0 = blockIdx.x * 32;
    int tid = threadIdx.x;
    #pragma unroll
    for (int i = tid; i < 32 * 128; i += 256) {
        int c = i >> 5, p = i & 31;
        lt[p][c] = x2[((size_t)(n * CCH + c)) * LL + pix0 + p];
    }
    __syncthreads();
    #pragma unroll
    for (int i = tid; i < 32 * 128; i += 256) {
        int p = i >> 7, c = i & 127;
        float v = lt[p][c];
        u16 h = f2bf(v);
        size_t o = (size_t)(n * LL + pix0 + p) * CCH + c;
        Xh[o] = h;
        Xl[o] = f2bf(v - bf2f(h));
    }
    if (tid < 32) {
        float s = 0.0f;
        for (int c = 0; c < CCH; c++) { float t = lt[tid][c]; s += t * t; }
        pxn[n * LL + pix0 + tid] = s;
    }
}

__global__ __launch_bounds__(256) void boxnorm_k(const float* __restrict__ pxn,
                                                 const float* __restrict__ mask,
                                                 float* __restrict__ rnorm,
                                                 float* __restrict__ mmb) {
    int n = blockIdx.z;
    int p = blockIdx.x * 256 + threadIdx.x;
    int i = p / HS, j = p - (p / HS) * HS;
    float s = 0.0f, msum = 0.0f;
    for (int di = -1; di <= 1; di++)
        for (int dj = -1; dj <= 1; dj++) {
            int ii = i + di, jj = j + dj;
            if (ii >= 0 && ii < HS && jj >= 0 && jj < HS) {
                s += pxn[n * LL + ii * HS + jj];
                msum += mask[(n * HS + ii) * HS + jj];
            }
        }
    rnorm[n * LL + p] = 1.0f / fmaxf(sqrtf(s), 1e-4f);
    mmb[n * LL + p] = (msum == 0.0f) ? 1.0f : 0.0f;
}

// ---------------------------------------------------------------------------
__global__ __launch_bounds__(256) void scan_k(const float* __restrict__ mmb,
                                              int* __restrict__ cmap,
                                              int* __restrict__ lidx,
                                              int* __restrict__ meta) {
    int n = blockIdx.x;
    int tid = threadIdx.x, lane = tid & 63, wid = tid >> 6;
    __shared__ int wtot[4];
    int base = tid * 9;
    int flags[9], cnt = 0;
    #pragma unroll
    for (int e = 0; e < 9; e++) {
        flags[e] = (mmb[n * LL + base + e] != 0.0f) ? 1 : 0;
        cnt += flags[e];
    }
    int inc = cnt;
    #pragma unroll
    for (int o = 1; o < 64; o <<= 1) {
        int v = __shfl_up(inc, o);
        if (lane >= o) inc += v;
    }
    if (lane == 63) wtot[wid] = inc;
    __syncthreads();
    int woff = 0;
    for (int wv = 0; wv < wid; wv++) woff += wtot[wv];
    int k = woff + inc - cnt;
    #pragma unroll
    for (int e = 0; e < 9; e++) {
        int l = base + e;
        if (flags[e]) { cmap[n * LL + l] = k; lidx[n * LL + k] = l; k++; }
        else cmap[n * LL + l] = -1;
    }
    if (tid == 255) {
        int Knz = woff + inc;
        int KA = ((Knz + 191) / 192) * 64;
        if (KA < 64) KA = 64;
        meta[n * 2] = Knz;
        meta[n * 2 + 1] = KA;
    }
}

// ---------------------------------------------------------------------------
// S[u][v] = Xt[u].Xt[v] (symmetric): triangular grid (171 blocks). Transposed
// tile written ONLY for subdiagonal tiles (bj==bi+1) — the only lower-triangle
// elements zsumexp reads are within 47 of the diagonal.
__global__ __launch_bounds__(256) void sgemm_k(const u16* __restrict__ Xh, const u16* __restrict__ Xl,
                                               float* __restrict__ S) {
    __shared__ __align__(16) u16 Ah[4096], Al[4096], Bh[4096], Bl[4096];
    int tid = threadIdx.x, w = tid >> 6, lane = tid & 63;
    int t = blockIdx.x, bi = 0;
    while (t >= 18 - bi) { t -= 18 - bi; bi++; }
    int bj = bi + t;
    int m0 = bi * 128, n0 = bj * 128;
    int srow = lane & 15, sk = (lane >> 4) * 8;
    size_t a1 = (size_t)(m0 + w * 16 + srow) * CCH + sk;
    size_t a2 = a1 + (size_t)64 * CCH;
    size_t b1 = (size_t)(n0 + w * 16 + srow) * CCH + sk;
    size_t b2 = b1 + (size_t)64 * CCH;
    int wm = (w >> 1) * 64, wn = (w & 1) * 64;
    int ga = (w >> 1) * 4, gb = (w & 1) * 4;
    f32x4 acc[4][4];
    #pragma unroll
    for (int i = 0; i < 4; i++)
        #pragma unroll
        for (int j = 0; j < 4; j++) acc[i][j] = (f32x4)0.0f;

    for (int k0 = 0; k0 < CCH; k0 += 32) {
        if (k0) __syncthreads();
        gll16(Xh + a1 + k0, Ah + w * 512);
        gll16(Xh + a2 + k0, Ah + (w + 4) * 512);
        gll16(Xl + a1 + k0, Al + w * 512);
        gll16(Xl + a2 + k0, Al + (w + 4) * 512);
        gll16(Xh + b1 + k0, Bh + w * 512);
        gll16(Xh + b2 + k0, Bh + (w + 4) * 512);
        gll16(Xl + b1 + k0, Bl + w * 512);
        gll16(Xl + b2 + k0, Bl + (w + 4) * 512);
        __syncthreads();
        bfx8 ah[4], al[4], bh[4], bl[4];
        #pragma unroll
        for (int i = 0; i < 4; i++) {
            ah[i] = *(const bfx8*)&Ah[(ga + i) * 512 + lane * 8];
            al[i] = *(const bfx8*)&Al[(ga + i) * 512 + lane * 8];
        }
        #pragma unroll
        for (int j = 0; j < 4; j++) {
            bh[j] = *(const bfx8*)&Bh[(gb + j) * 512 + lane * 8];
            bl[j] = *(const bfx8*)&Bl[(gb + j) * 512 + lane * 8];
        }
        #pragma unroll
        for (int i = 0; i < 4; i++)
            #pragma unroll
            for (int j = 0; j < 4; j++) {
                acc[i][j] = __builtin_amdgcn_mfma_f32_16x16x32_bf16(ah[i], bh[j], acc[i][j], 0, 0, 0);
                acc[i][j] = __builtin_amdgcn_mfma_f32_16x16x32_bf16(ah[i], bl[j], acc[i][j], 0, 0, 0);
                acc[i][j] = __builtin_amdgcn_mfma_f32_16x16x32_bf16(al[i], bh[j], acc[i][j], 0, 0, 0);
            }
    }
    bool wrT = (bj == bi + 1);
    #pragma unroll
    for (int j = 0; j < 4; j++) {
        int col = n0 + wn + j * 16 + (lane & 15);
        #pragma unroll
        for (int i = 0; i < 4; i++) {
            int rbase = m0 + wm + i * 16 + (lane >> 4) * 4;
            #pragma unroll
            for (int r = 0; r < 4; r++)
                S[(size_t)(rbase + r) * LL + col] = acc[i][j][r];
            if (wrT)
                *(f32x4*)&S[(size_t)col * LL + rbase] = acc[i][j];
        }
    }
}

// ---------------------------------------------------------------------------
// Fused diagonal shift-sum + partial softmax. Triangular (pi<=li) block:
// builds the Z-tile in LDS, computes logits, per-tile-row max/sumexp stats
// (both orientations), writes unnormalized bf16 exp(logit - m_b) to Tbu.
// Z is never materialized.
__global__ __launch_bounds__(256) void zsumexp_k(const float* __restrict__ S,
                                                 const float* __restrict__ rnorm,
                                                 const float* __restrict__ mmb,
                                                 const float* __restrict__ mask_all,
                                                 u16* __restrict__ Tbu,
                                                 float* __restrict__ statm,
                                                 float* __restrict__ stats, int n) {
    __shared__ float lt[3][48][49];
    __shared__ float zt[48][49];
    __shared__ float rcA[48], mmA[48], maA[48];
    __shared__ float rcB[48], mmB[48], maB[48];
    __shared__ float rowm[48];
    int t = blockIdx.x, pi = 0;
    while (t >= HS - pi) { t -= HS - pi; pi++; }
    int li = pi + t;
    int tid = threadIdx.x;
    #pragma unroll
    for (int di = 0; di < 3; di++) {
        int a = pi + di - 1, b = li + di - 1;
        bool valid = (a >= 0) && (a < HS) && (b >= 0) && (b < HS);
        const float* base = S + ((size_t)a * HS) * LL + b * HS;
        #pragma unroll
        for (int k = 0; k < 9; k++) {
            int idx = tid + k * 256;
            int r = idx / HS, c = idx - r * HS;
            lt[di][r][c] = valid ? base[(size_t)r * LL + c] : 0.0f;
        }
    }
    if (tid < 48) {
        int lcol = n * LL + li * HS + tid;
        rcA[tid] = rnorm[lcol] * 10.0f;
        mmA[tid] = mmb[lcol];
        maB[tid] = mask_all[lcol];
        int pcol = n * LL + pi * HS + tid;
        rcB[tid] = rnorm[pcol] * 10.0f;
        mmB[tid] = mmb[pcol];
        maA[tid] = mask_all[pcol];
    }
    __syncthreads();
    #pragma unroll
    for (int k = 0; k < 9; k++) {
        int idx = tid + k * 256;
        int pj = idx / HS, lj = idx - pj * HS;
        float acc = 0.0f;
        #pragma unroll
        for (int dj = -1; dj <= 1; dj++) {
            int rr = pj + dj, cc = lj + dj;
            if (rr >= 0 && rr < HS && cc >= 0 && cc < HS)
                acc += lt[0][rr][cc] + lt[1][rr][cc] + lt[2][rr][cc];
        }
        zt[pj][lj] = acc;
    }
    __syncthreads();
    // primary: rows p=pi*48+pj, cols l=li*48+lj; stats over unmasked cols only
    if (tid < 48) {
        float ma_ = maA[tid];
        float m = -3.0e38f;
        for (int lj = 0; lj < 48; lj++)
            if (mmA[lj] != 0.0f) m = fmaxf(m, zt[tid][lj] * rcA[lj] * ma_);
        float s = 0.0f;
        if (m > -1.0e37f)
            for (int lj = 0; lj < 48; lj++)
                if (mmA[lj] != 0.0f) s += __expf(zt[tid][lj] * rcA[lj] * ma_ - m);
        rowm[tid] = m;
        statm[(size_t)(pi * HS + tid) * HS + li] = m;
        stats[(size_t)(pi * HS + tid) * HS + li] = s;
    }
    __syncthreads();
    #pragma unroll
    for (int k = 0; k < 9; k++) {
        int idx = tid + k * 256;
        int pj = idx / HS, lj = idx - pj * HS;
        float lg = zt[pj][lj] * rcA[lj] * maA[pj];
        Tbu[(size_t)(pi * HS + pj) * LL + li * HS + lj] = f2bf(__expf(lg - rowm[pj]));
    }
    if (pi != li) {   // transposed tile: rows l'=li*48+lj, cols p''=pi*48+pj
        __syncthreads();
        if (tid < 48) {
            float ma_ = maB[tid];
            float m = -3.0e38f;
            for (int pj = 0; pj < 48; pj++)
                if (mmB[pj] != 0.0f) m = fmaxf(m, zt[pj][tid] * rcB[pj] * ma_);
            float s = 0.0f;
            if (m > -1.0e37f)
                for (int pj = 0; pj < 48; pj++)
                    if (mmB[pj] != 0.0f) s += __expf(zt[pj][tid] * rcB[pj] * ma_ - m);
            rowm[tid] = m;
            statm[(size_t)(li * HS + tid) * HS + pi] = m;
            stats[(size_t)(li * HS + tid) * HS + pi] = s;
        }
        __syncthreads();
        #pragma unroll
        for (int k = 0; k < 9; k++) {
            int idx = tid + k * 256;
            int lj = idx / HS, pj = idx - lj * HS;
            float lg = zt[pj][lj] * rcB[pj] * maB[lj];
            Tbu[(size_t)(li * HS + lj) * LL + pi * HS + pj] = f2bf(__expf(lg - rowm[lj]));
        }
    }
}

// ---------------------------------------------------------------------------
// Combine per-block stats (m = max(0, max_b m_b); S = sum s_b e^{m_b-m} +
// nmask*e^{-m} — masked cols have logit exactly 0), rescale Tbu, apply
// boost/ma/clamp, write compacted Tbc + zero-pad.
__global__ __launch_bounds__(256) void fixup_k(const u16* __restrict__ Tbu,
                                               u16* __restrict__ Tbc,
                                               const float* __restrict__ statm,
                                               const float* __restrict__ stats,
                                               const float* __restrict__ mask_all,
                                               const int* __restrict__ cmap,
                                               const int* __restrict__ meta, int n) {
    int p = blockIdx.x, tid = threadIdx.x;
    __shared__ float fac[48];
    __shared__ float red[2];
    int Knz = meta[n * 2], KA3 = 3 * meta[n * 2 + 1];
    float nmask = (float)(LL - Knz);
    float mb = (tid < 48) ? statm[(size_t)p * HS + tid] : -3.0e38f;
    if (tid < 64) {
        float m = mb;
        #pragma unroll
        for (int o = 32; o; o >>= 1) m = fmaxf(m, __shfl_down(m, o));
        if (tid == 0) red[0] = (nmask > 0.0f) ? fmaxf(m, 0.0f) : m;
    }
    __syncthreads();
    float m = red[0];
    if (tid < 64) {
        float sb = 0.0f;
        if (tid < 48) {
            float f = __expf(mb - m);
            fac[tid] = f;
            sb = stats[(size_t)p * HS + tid] * f;
        }
        #pragma unroll
        for (int o = 32; o; o >>= 1) sb += __shfl_down(sb, o);
        if (tid == 0) red[1] = 1.0f / (sb + nmask * __expf(-m));
    }
    __syncthreads();
    float inv = red[1];
    int pi = p / HS, pj = p - pi * HS;
    float ma = mask_all[n * LL + p];
    #pragma unroll
    for (int e = 0; e < 9; e++) {
        int l = tid + e * 256;
        int cm = cmap[n * LL + l];
        if (cm >= 0) {
            int li = l / HS, lj = l - li * HS;
            bool nb = (li == pi && (lj == pj - 1 || lj == pj + 1)) ||
                      (lj == pj && (li == pi - 1 || li == pi + 1));
            float w = bf2f(Tbu[(size_t)p * LL + l]) * fac[li] * inv * (nb ? 1.5f : 1.0f) * ma;
            Tbc[(size_t)p * LL + cm] = f2bf(fmaxf(w, 1e-8f));
        }
    }
    for (int k = Knz + tid; k < KA3; k += 256) Tbc[(size_t)p * LL + k] = 0;
}

// ---------------------------------------------------------------------------
__global__ __launch_bounds__(256) void build_W_k(const float* __restrict__ x1,
                                                 u16* __restrict__ Wtc,
                                                 const int* __restrict__ lidx,
                                                 const int* __restrict__ meta, int n) {
    int idx = blockIdx.x * 256 + threadIdx.x;
    int k = idx % LL, f = idx / LL;
    int Knz = meta[n * 2];
    u16 out = 0;
    if (k < Knz) {
        int l = lidx[n * LL + k];
        int c = f & 127, tap = f >> 7;
        int ky = tap >> 2, kx = tap & 3;
        int li = l / HS, lj = l - (l / HS) * HS;
        int yy = 2 * li - 1 + ky, xx = 2 * lj - 1 + kx;
        float v = 0.0f;
        if (yy >= 0 && yy < HO && xx >= 0 && xx < HO)
            v = x1[((n * CCH + c) * HO + yy) * HO + xx];
        out = f2bf(v);
    }
    Wtc[idx] = out;
}

// ---------------------------------------------------------------------------
__global__ __launch_bounds__(256) void gemm2_k(const u16* __restrict__ Tbc, const u16* __restrict__ Wtc,
                                               u16* __restrict__ V,
                                               const int* __restrict__ meta, int n) {
    __shared__ __align__(16) u16 As[8192], Bs[8192];
    int tid = threadIdx.x, w = tid >> 6, lane = tid & 63;
    int m0 = blockIdx.x * 128, n0 = blockIdx.y * 128;
    int KA = meta[n * 2 + 1];
    int koff = blockIdx.z * KA;
    int srow = lane & 15, sk = (lane >> 4) * 8;
    size_t a1 = (size_t)(m0 + w * 16 + srow) * LL + koff + sk;
    size_t a2 = a1 + (size_t)64 * LL;
    size_t b1 = (size_t)(n0 + w * 16 + srow) * LL + koff + sk;
    size_t b2 = b1 + (size_t)64 * LL;
    int wm = (w >> 1) * 64, wn = (w & 1) * 64;
    int ga = (w >> 1) * 4, gb = (w & 1) * 4;
    f32x4 acc[4][4];
    #pragma unroll
    for (int i = 0; i < 4; i++)
        #pragma unroll
        for (int j = 0; j < 4; j++) acc[i][j] = (f32x4)0.0f;

    for (int k0 = 0; k0 < KA; k0 += 64) {
        if (k0) __syncthreads();
        gll16(Tbc + a1 + k0,      As + w * 1024);
        gll16(Tbc + a1 + k0 + 32, As + w * 1024 + 512);
        gll16(Tbc + a2 + k0,      As + (w + 4) * 1024);
        gll16(Tbc + a2 + k0 + 32, As + (w + 4) * 1024 + 512);
        gll16(Wtc + b1 + k0,      Bs + w * 1024);
        gll16(Wtc + b1 + k0 + 32, Bs + w * 1024 + 512);
        gll16(Wtc + b2 + k0,      Bs + (w + 4) * 1024);
        gll16(Wtc + b2 + k0 + 32, Bs + (w + 4) * 1024 + 512);
        __syncthreads();
        #pragma unroll
        for (int kk = 0; kk < 2; kk++) {
            bfx8 af[4], bf[4];
            #pragma unroll
            for (int i = 0; i < 4; i++) af[i] = *(const bfx8*)&As[(ga + i) * 1024 + kk * 512 + lane * 8];
            #pragma unroll
            for (int j = 0; j < 4; j++) bf[j] = *(const bfx8*)&Bs[(gb + j) * 1024 + kk * 512 + lane * 8];
            #pragma unroll
            for (int i = 0; i < 4; i++)
                #pragma unroll
                for (int j = 0; j < 4; j++)
                    acc[i][j] = __builtin_amdgcn_mfma_f32_16x16x32_bf16(af[i], bf[j], acc[i][j], 0, 0, 0);
        }
    }
    u16* Vb = V + (size_t)blockIdx.z * VHALF;
    #pragma unroll
    for (int j = 0; j < 4; j++) {
        int f = n0 + wn + j * 16 + (lane & 15);
        #pragma unroll
        for (int i = 0; i < 4; i++) {
            int rbase = m0 + wm + i * 16 + (lane >> 4) * 4;
            #pragma unroll
            for (int r = 0; r < 4; r++)
                Vb[(size_t)(rbase + r) * KW + f] = f2bf(0.25f * acc[i][j][r]);
        }
    }
}

// ---------------------------------------------------------------------------
__global__ __launch_bounds__(256) void gather_k(const u16* __restrict__ V,
                                                u16* __restrict__ yT, int n) {
    int idx = blockIdx.x * 256 + threadIdx.x;      // PIX*128
    int c = idx & 127, pix = idx >> 7;
    int yy = pix / HO, xx = pix - yy * HO;
    int ky0 = (yy + 1) & 1, kx0 = (xx + 1) & 1;
    float s = 0.0f;
    #pragma unroll
    for (int a = 0; a < 2; a++) {
        int ky = ky0 + a * 2;
        int py = yy + 1 - ky;
        if (py < 0 || py >= HO) continue;
        int pi = py >> 1;
        #pragma unroll
        for (int b = 0; b < 2; b++) {
            int kx = kx0 + b * 2;
            int px = xx + 1 - kx;
            if (px < 0 || px >= HO) continue;
            int pj = px >> 1;
            size_t off = (size_t)(pi * HS + pj) * KW + (ky * 4 + kx) * 128 + c;
            s += bf2f(V[off]) + bf2f(V[VHALF + off]) + bf2f(V[2 * VHALF + off]);
        }
    }
    yT[(size_t)(n * PIX + pix) * CCH + c] = f2bf(s);
}

// ---------------------------------------------------------------------------
__global__ __launch_bounds__(256) void wprep_k(const float* __restrict__ fw,
                                               u16* __restrict__ Wf) {
    int idx = blockIdx.x * 256 + threadIdx.x;
    int c = idx & 127;
    int tap = (idx >> 7) % 9;
    int go = idx / (128 * 9);
    Wf[idx] = f2bf(fw[((size_t)go * 128 + c) * 9 + tap]);
}

// ---------------------------------------------------------------------------
__global__ __launch_bounds__(256) void fuse_mfma_k(const u16* __restrict__ yT,
                                                   const u16* __restrict__ Wf,
                                                   const float* __restrict__ fb,
                                                   float* __restrict__ out) {
    int n = blockIdx.z, g = blockIdx.y;
    const int d = 1 << g;
    int tid = threadIdx.x, wv = tid >> 6, lane = tid & 63;
    int pix0 = blockIdx.x * 64 + wv * 16;
    int h = pix0 / HO, w0 = pix0 - h * HO;
    int m = lane & 15, q = lane >> 4;
    int oc = m;
    const u16* brow = Wf + ((size_t)(g * 16 + oc) * 9) * CCH + q * 8;
    f32x4 acc = (f32x4)0.0f;

    #pragma unroll
    for (int tap = 0; tap < 9; tap++) {
        int dy = (tap / 3 - 1) * d, dx = (tap % 3 - 1) * d;
        int hh = h + dy;
        int ww = w0 + m + dx;
        bool v = (hh >= 0) & (hh < HO) & (ww >= 0) & (ww < HO);
        const u16* arow = yT + ((size_t)(n * PIX + hh * HO + ww)) * CCH + q * 8;
        const u16* bt = brow + tap * CCH;
        #pragma unroll
        for (int c0 = 0; c0 < CCH; c0 += 32) {
            bfx8 af = (bfx8)0;
            if (v) af = *(const bfx8*)(arow + c0);
            bfx8 bf = *(const bfx8*)(bt + c0);
            acc = __builtin_amdgcn_mfma_f32_16x16x32_bf16(af, bf, acc, 0, 0, 0);
        }
    }
    float bias = fb[g * 16 + oc];
    f32x4 o;
    #pragma unroll
    for (int r = 0; r < 4; r++) o[r] = fmaxf(acc[r] + bias, 0.0f);
    size_t oi = ((size_t)(n * 64 + g * 16 + oc)) * PIX + pix0 + q * 4;
    *(f32x4*)&out[oi] = o;
}

// ---------------------------------------------------------------------------
extern "C" void kernel_launch(void* const* d_in, const int* in_sizes, int n_in,
                              void* d_out, int out_size, void* d_ws, size_t ws_size,
                              hipStream_t stream) {
    const float* x1       = (const float*)d_in[0];
    const float* x2       = (const float*)d_in[1];
    const float* mask     = (const float*)d_in[2];
    const float* mask_all = (const float*)d_in[3];
    const float* fw       = (const float*)d_in[4];
    const float* fb       = (const float*)d_in[5];
    float* out = (float*)d_out;
    char* wsb  = (char*)d_ws;

    u16*   Xh    = (u16*)(wsb + XTH_B);
    u16*   Xl    = (u16*)(wsb + XTL_B);
    float* pxn   = (float*)(wsb + PXN_B);
    float* rnorm = (float*)(wsb + NRM_B);
    float* mmb   = (float*)(wsb + MM_B);
    u16*   Wf    = (u16*)(wsb + WF_B);
    u16*   Wtc   = (u16*)(wsb + WT_B);
    float* S     = (float*)(wsb + S_B);
    u16*   Tbc   = (u16*)(wsb + TBC_B);    // aliases dead S head
    u16*   Tbu   = (u16*)(wsb + TBU_B);    // dead after fixup
    u16*   V     = (u16*)(wsb + V_B);      // overlaps dead S tail + Tbu (serial)
    u16*   yT    = (u16*)(wsb + YT_B);
    int*   cmap  = (int*)(wsb + CMAP_B);
    int*   lidx  = (int*)(wsb + LIDX_B);
    int*   meta  = (int*)(wsb + MET_B);
    float* statm = (float*)(wsb + STM_B);
    float* stats = (float*)(wsb + STS_B);

    wprep_k<<<(64 * 9 * 128) / 256, 256, 0, stream>>>(fw, Wf);
    xprep_k<<<dim3(LL / 32, 1, NB), 256, 0, stream>>>(x2, Xh, Xl, pxn);
    boxnorm_k<<<dim3(LL / 256, 1, NB), 256, 0, stream>>>(pxn, mask, rnorm, mmb);
    scan_k<<<NB, 256, 0, stream>>>(mmb, cmap, lidx, meta);

    for (int n = 0; n < NB; n++) {
        sgemm_k<<<171, 256, 0, stream>>>(Xh + (size_t)n * LL * CCH,
                                         Xl + (size_t)n * LL * CCH, S);
        zsumexp_k<<<HS * (HS + 1) / 2, 256, 0, stream>>>(S, rnorm, mmb, mask_all,
                                                         Tbu, statm, stats, n);
        fixup_k<<<LL, 256, 0, stream>>>(Tbu, Tbc, statm, stats, mask_all, cmap, meta, n);
        build_W_k<<<(KW * LL) / 256, 256, 0, stream>>>(x1, Wtc, lidx, meta, n);
        gemm2_k<<<dim3(18, 16, 3), 256, 0, stream>>>(Tbc, Wtc, V, meta, n);
        gather_k<<<(PIX * 128) / 256, 256, 0, stream>>>(V, yT, n);
    }
    fuse_mfma_k<<<dim3(PIX / 64, 4, NB), 256, 0, stream>>>(yT, Wf, fb, out);
}

// Round 13
// 323.149 us; speedup vs baseline: 1.2078x; 1.2078x over previous
//
#include <hip/hip_runtime.h>
#include <math.h>

typedef unsigned short u16;
typedef unsigned int   u32;
typedef float f32x4 __attribute__((ext_vector_type(4)));
typedef short bfx8  __attribute__((ext_vector_type(8)));

#define NB   2
#define CCH  128
#define HS   48
#define LL   2304        // 48*48
#define KW   2048        // 128*4*4
#define HO   96
#define PIX  9216        // 96*96
#define VHALF ((size_t)LL * KW)   // elements per split-K V buffer (9,437,184 B)

// Workspace layout (r11-proven; peak < 60.2 MB budget)
#define XTH_B 0                  // x2^T hi bf16 [2][2304][128] = 1,179,648
#define XTL_B 1179648            // x2^T lo bf16
#define PXN_B 2359296            // per-pixel sqnorm fp32 [2][2304]
#define NRM_B 2377728            // 1/norms fp32 [2][2304]
#define MM_B  2396160            // mm flags fp32 [2][2304]
#define WF_B  2414592            // fuse weights bf16 [64][9][128] = 147,456
#define WT_B  2562048            // W^T(compacted) bf16 = 9,437,184
#define S_B   11999232           // S fp32 21,233,664 (dead after zsum)
#define TBD_B S_B                // compacted Tbc bf16 (aliases dead S)
#define V_B   (S_B + 10616832)   // V0/V1/V2 bf16 3x9,437,184; overlaps dead Z. Serially safe.
#define Z_B   33232896           // Z fp32 21,233,664 (dead after softmax)
#define YT_B  54466560           // yT bf16 [2][9216][128] = 4,718,592
#define CMAP_B 59185152          // int cmap [2][2304]
#define LIDX_B (CMAP_B + 18432)  // int lidx [2][2304]
#define MET_B  (LIDX_B + 18432)  // int meta [2][2]

__device__ __forceinline__ u16 f2bf(float f) {      // round-to-nearest-even
    u32 u = __float_as_uint(f);
    u32 r = (u + 0x7fffu + ((u >> 16) & 1u)) >> 16;
    return (u16)r;
}
__device__ __forceinline__ float bf2f(u16 h) {
    return __uint_as_float(((u32)h) << 16);
}
__device__ __forceinline__ void gll16(const void* g, void* l) {
    __builtin_amdgcn_global_load_lds((const __attribute__((address_space(1))) void*)g,
                                     (__attribute__((address_space(3))) void*)l, 16, 0, 0);
}

// ---------------------------------------------------------------------------
__global__ __launch_bounds__(256) void xprep_k(const float* __restrict__ x2,
                                               u16* __restrict__ Xh, u16* __restrict__ Xl,
                                               float* __restrict__ pxn) {
    __shared__ float lt[32][130];
    int n = blockIdx.z;
    int pix0 = blockIdx.x * 32;
    int tid = threadIdx.x;
    #pragma unroll
    for (int i = tid; i < 32 * 128; i += 256) {
        int c = i >> 5, p = i & 31;
        lt[p][c] = x2[((size_t)(n * CCH + c)) * LL + pix0 + p];
    }
    __syncthreads();
    #pragma unroll
    for (int i = tid; i < 32 * 128; i += 256) {
        int p = i >> 7, c = i & 127;
        float v = lt[p][c];
        u16 h = f2bf(v);
        size_t o = (size_t)(n * LL + pix0 + p) * CCH + c;
        Xh[o] = h;
        Xl[o] = f2bf(v - bf2f(h));
    }
    if (tid < 32) {
        float s = 0.0f;
        for (int c = 0; c < CCH; c++) { float t = lt[tid][c]; s += t * t; }
        pxn[n * LL + pix0 + tid] = s;
    }
}

__global__ __launch_bounds__(256) void boxnorm_k(const float* __restrict__ pxn,
                                                 const float* __restrict__ mask,
                                                 float* __restrict__ rnorm,
                                                 float* __restrict__ mmb) {
    int n = blockIdx.z;
    int p = blockIdx.x * 256 + threadIdx.x;
    int i = p / HS, j = p - (p / HS) * HS;
    float s = 0.0f, msum = 0.0f;
    for (int di = -1; di <= 1; di++)
        for (int dj = -1; dj <= 1; dj++) {
            int ii = i + di, jj = j + dj;
            if (ii >= 0 && ii < HS && jj >= 0 && jj < HS) {
                s += pxn[n * LL + ii * HS + jj];
                msum += mask[(n * HS + ii) * HS + jj];
            }
        }
    rnorm[n * LL + p] = 1.0f / fmaxf(sqrtf(s), 1e-4f);
    mmb[n * LL + p] = (msum == 0.0f) ? 1.0f : 0.0f;
}

// ---------------------------------------------------------------------------
__global__ __launch_bounds__(256) void scan_k(const float* __restrict__ mmb,
                                              int* __restrict__ cmap,
                                              int* __restrict__ lidx,
                                              int* __restrict__ meta) {
    int n = blockIdx.x;
    int tid = threadIdx.x, lane = tid & 63, wid = tid >> 6;
    __shared__ int wtot[4];
    int base = tid * 9;
    int flags[9], cnt = 0;
    #pragma unroll
    for (int e = 0; e < 9; e++) {
        flags[e] = (mmb[n * LL + base + e] != 0.0f) ? 1 : 0;
        cnt += flags[e];
    }
    int inc = cnt;
    #pragma unroll
    for (int o = 1; o < 64; o <<= 1) {
        int v = __shfl_up(inc, o);
        if (lane >= o) inc += v;
    }
    if (lane == 63) wtot[wid] = inc;
    __syncthreads();
    int woff = 0;
    for (int wv = 0; wv < wid; wv++) woff += wtot[wv];
    int k = woff + inc - cnt;
    #pragma unroll
    for (int e = 0; e < 9; e++) {
        int l = base + e;
        if (flags[e]) { cmap[n * LL + l] = k; lidx[n * LL + k] = l; k++; }
        else cmap[n * LL + l] = -1;
    }
    if (tid == 255) {
        int Knz = woff + inc;
        int KA = ((Knz + 191) / 192) * 64;
        if (KA < 64) KA = 64;
        meta[n * 2] = Knz;
        meta[n * 2 + 1] = KA;
    }
}

// ---------------------------------------------------------------------------
// S[u][v] = Xt[u].Xt[v] (symmetric): triangular grid (171 blocks). Transposed
// tile written only for subdiagonal tiles (bj==bi+1) — all zsum needs.
__global__ __launch_bounds__(256) void sgemm_k(const u16* __restrict__ Xh, const u16* __restrict__ Xl,
                                               float* __restrict__ S) {
    __shared__ __align__(16) u16 Ah[4096], Al[4096], Bh[4096], Bl[4096];
    int tid = threadIdx.x, w = tid >> 6, lane = tid & 63;
    int t = blockIdx.x, bi = 0;
    while (t >= 18 - bi) { t -= 18 - bi; bi++; }
    int bj = bi + t;
    int m0 = bi * 128, n0 = bj * 128;
    int srow = lane & 15, sk = (lane >> 4) * 8;
    size_t a1 = (size_t)(m0 + w * 16 + srow) * CCH + sk;
    size_t a2 = a1 + (size_t)64 * CCH;
    size_t b1 = (size_t)(n0 + w * 16 + srow) * CCH + sk;
    size_t b2 = b1 + (size_t)64 * CCH;
    int wm = (w >> 1) * 64, wn = (w & 1) * 64;
    int ga = (w >> 1) * 4, gb = (w & 1) * 4;
    f32x4 acc[4][4];
    #pragma unroll
    for (int i = 0; i < 4; i++)
        #pragma unroll
        for (int j = 0; j < 4; j++) acc[i][j] = (f32x4)0.0f;

    for (int k0 = 0; k0 < CCH; k0 += 32) {
        if (k0) __syncthreads();
        gll16(Xh + a1 + k0, Ah + w * 512);
        gll16(Xh + a2 + k0, Ah + (w + 4) * 512);
        gll16(Xl + a1 + k0, Al + w * 512);
        gll16(Xl + a2 + k0, Al + (w + 4) * 512);
        gll16(Xh + b1 + k0, Bh + w * 512);
        gll16(Xh + b2 + k0, Bh + (w + 4) * 512);
        gll16(Xl + b1 + k0, Bl + w * 512);
        gll16(Xl + b2 + k0, Bl + (w + 4) * 512);
        __syncthreads();
        bfx8 ah[4], al[4], bh[4], bl[4];
        #pragma unroll
        for (int i = 0; i < 4; i++) {
            ah[i] = *(const bfx8*)&Ah[(ga + i) * 512 + lane * 8];
            al[i] = *(const bfx8*)&Al[(ga + i) * 512 + lane * 8];
        }
        #pragma unroll
        for (int j = 0; j < 4; j++) {
            bh[j] = *(const bfx8*)&Bh[(gb + j) * 512 + lane * 8];
            bl[j] = *(const bfx8*)&Bl[(gb + j) * 512 + lane * 8];
        }
        #pragma unroll
        for (int i = 0; i < 4; i++)
            #pragma unroll
            for (int j = 0; j < 4; j++) {
                acc[i][j] = __builtin_amdgcn_mfma_f32_16x16x32_bf16(ah[i], bh[j], acc[i][j], 0, 0, 0);
                acc[i][j] = __builtin_amdgcn_mfma_f32_16x16x32_bf16(ah[i], bl[j], acc[i][j], 0, 0, 0);
                acc[i][j] = __builtin_amdgcn_mfma_f32_16x16x32_bf16(al[i], bh[j], acc[i][j], 0, 0, 0);
            }
    }
    bool wrT = (bj == bi + 1);
    #pragma unroll
    for (int j = 0; j < 4; j++) {
        int col = n0 + wn + j * 16 + (lane & 15);
        #pragma unroll
        for (int i = 0; i < 4; i++) {
            int rbase = m0 + wm + i * 16 + (lane >> 4) * 4;
            #pragma unroll
            for (int r = 0; r < 4; r++)
                S[(size_t)(rbase + r) * LL + col] = acc[i][j][r];
            if (wrT)
                *(f32x4*)&S[(size_t)col * LL + rbase] = acc[i][j];
        }
    }
}

// ---------------------------------------------------------------------------
// Diagonal shift-sum (symmetric): triangular (pi<=li) grid of 1176 blocks.
__global__ __launch_bounds__(256) void zsum_k(const float* __restrict__ S,
                                              float* __restrict__ Z) {
    __shared__ float lt[3][48][49];
    int t = blockIdx.x, pi = 0;
    while (t >= HS - pi) { t -= HS - pi; pi++; }
    int li = pi + t;
    int tid = threadIdx.x;
    #pragma unroll
    for (int di = 0; di < 3; di++) {
        int a = pi + di - 1, b = li + di - 1;
        bool valid = (a >= 0) && (a < HS) && (b >= 0) && (b < HS);
        const float* base = S + ((size_t)a * HS) * LL + b * HS;
        #pragma unroll
        for (int k = 0; k < 9; k++) {
            int idx = tid + k * 256;
            int r = idx / HS, c = idx - r * HS;
            lt[di][r][c] = valid ? base[(size_t)r * LL + c] : 0.0f;
        }
    }
    __syncthreads();
    #pragma unroll
    for (int k = 0; k < 9; k++) {
        int idx = tid + k * 256;
        int pj = idx / HS, lj = idx - pj * HS;
        float acc = 0.0f;
        #pragma unroll
        for (int dj = -1; dj <= 1; dj++) {
            int rr = pj + dj, cc = lj + dj;
            if (rr >= 0 && rr < HS && cc >= 0 && cc < HS)
                acc += lt[0][rr][cc] + lt[1][rr][cc] + lt[2][rr][cc];
        }
        Z[((size_t)pi * HS + pj) * LL + li * HS + lj] = acc;
    }
    if (pi != li) {
        #pragma unroll
        for (int k = 0; k < 9; k++) {
            int idx = tid + k * 256;
            int lj = idx / HS, pj = idx - lj * HS;
            float acc = 0.0f;
            #pragma unroll
            for (int dj = -1; dj <= 1; dj++) {
                int rr = pj + dj, cc = lj + dj;
                if (rr >= 0 && rr < HS && cc >= 0 && cc < HS)
                    acc += lt[0][rr][cc] + lt[1][rr][cc] + lt[2][rr][cc];
            }
            Z[((size_t)li * HS + lj) * LL + pi * HS + pj] = acc;
        }
    }
}

// ---------------------------------------------------------------------------
// Row softmax over Z -> COMPACTED bf16 Tbc row (scatter via cmap), zero-padded.
__global__ __launch_bounds__(256) void softmax_k(const float* __restrict__ Z,
                                                 u16* __restrict__ Tbc,
                                                 const float* __restrict__ rnorm,
                                                 const float* __restrict__ mmb,
                                                 const float* __restrict__ mask_all,
                                                 const int* __restrict__ cmap,
                                                 const int* __restrict__ meta, int n) {
    int p = blockIdx.x, tid = threadIdx.x;
    __shared__ float red[8];
    const float* row = Z + (size_t)p * LL;
    u16* orow = Tbc + (size_t)p * LL;
    float ma = mask_all[n * LL + p];
    float v[9], m9[9];
    float mx = -3.0e38f;
    #pragma unroll
    for (int e = 0; e < 9; e++) {
        int l = tid + e * 256;
        float m_ = mmb[n * LL + l];
        m9[e] = m_;
        float s = row[l] * rnorm[n * LL + l] * m_ * ma * 10.0f;
        v[e] = s;
        mx = fmaxf(mx, s);
    }
    #pragma unroll
    for (int o = 32; o; o >>= 1) mx = fmaxf(mx, __shfl_down(mx, o));
    int wid = tid >> 6, lane = tid & 63;
    if (lane == 0) red[wid] = mx;
    __syncthreads();
    mx = fmaxf(fmaxf(red[0], red[1]), fmaxf(red[2], red[3]));
    float sum = 0.0f;
    #pragma unroll
    for (int e = 0; e < 9; e++) { v[e] = __expf(v[e] - mx); sum += v[e]; }
    #pragma unroll
    for (int o = 32; o; o >>= 1) sum += __shfl_down(sum, o);
    if (lane == 0) red[4 + wid] = sum;
    __syncthreads();
    float inv = 1.0f / (red[4] + red[5] + red[6] + red[7]);
    int pi = p / HS, pj = p - (p / HS) * HS;
    #pragma unroll
    for (int e = 0; e < 9; e++) {
        int l = tid + e * 256;
        int cm = cmap[n * LL + l];
        if (cm >= 0) {
            int li = l / HS, lj = l - li * HS;
            bool nb = (li == pi && (lj == pj - 1 || lj == pj + 1)) ||
                      (lj == pj && (li == pi - 1 || li == pi + 1));
            float z = v[e] * inv * (nb ? 1.5f : 1.0f) * m9[e] * ma;
            orow[cm] = f2bf(fmaxf(z, 1e-8f));
        }
    }
    int Knz = meta[n * 2], KA3 = 3 * meta[n * 2 + 1];
    for (int k = Knz + tid; k < KA3; k += 256) orow[k] = 0;
}

// ---------------------------------------------------------------------------
__global__ __launch_bounds__(256) void build_W_k(const float* __restrict__ x1,
                                                 u16* __restrict__ Wtc,
                                                 const int* __restrict__ lidx,
                                                 const int* __restrict__ meta, int n) {
    int idx = blockIdx.x * 256 + threadIdx.x;
    int k = idx % LL, f = idx / LL;
    int Knz = meta[n * 2];
    u16 out = 0;
    if (k < Knz) {
        int l = lidx[n * LL + k];
        int c = f & 127, tap = f >> 7;
        int ky = tap >> 2, kx = tap & 3;
        int li = l / HS, lj = l - (l / HS) * HS;
        int yy = 2 * li - 1 + ky, xx = 2 * lj - 1 + kx;
        float v = 0.0f;
        if (yy >= 0 && yy < HO && xx >= 0 && xx < HO)
            v = x1[((n * CCH + c) * HO + yy) * HO + xx];
        out = f2bf(v);
    }
    Wtc[idx] = out;
}

// ---------------------------------------------------------------------------
// V[kb][p][f'] = 0.25 * sum_k Tbc[p][k]*Wtc[f'][k], compacted K. Split-K x3,
// BK=64, 4 waves of 64x64. 2x2-superblock swizzle: each XCD's round-robin
// block set shares m/n slabs (per-XCD L2 footprint ~1.2 MB vs ~5 MB scattered).
__global__ __launch_bounds__(256) void gemm2_k(const u16* __restrict__ Tbc, const u16* __restrict__ Wtc,
                                               u16* __restrict__ V,
                                               const int* __restrict__ meta, int n) {
    __shared__ __align__(16) u16 As[8192], Bs[8192];
    int tid = threadIdx.x, w = tid >> 6, lane = tid & 63;
    int lin = blockIdx.y * 18 + blockIdx.x;        // 0..287, bijective relabel
    int q = lin >> 2, rr2 = lin & 3;
    int sbx = q % 9, sby = q / 9;                  // 9x8 supergrid of 2x2
    int m0 = (sbx * 2 + (rr2 & 1)) * 128;
    int n0 = (sby * 2 + (rr2 >> 1)) * 128;
    int KA = meta[n * 2 + 1];
    int koff = blockIdx.z * KA;
    int srow = lane & 15, sk = (lane >> 4) * 8;
    size_t a1 = (size_t)(m0 + w * 16 + srow) * LL + koff + sk;
    size_t a2 = a1 + (size_t)64 * LL;
    size_t b1 = (size_t)(n0 + w * 16 + srow) * LL + koff + sk;
    size_t b2 = b1 + (size_t)64 * LL;
    int wm = (w >> 1) * 64, wn = (w & 1) * 64;
    int ga = (w >> 1) * 4, gb = (w & 1) * 4;
    f32x4 acc[4][4];
    #pragma unroll
    for (int i = 0; i < 4; i++)
        #pragma unroll
        for (int j = 0; j < 4; j++) acc[i][j] = (f32x4)0.0f;

    for (int k0 = 0; k0 < KA; k0 += 64) {
        if (k0) __syncthreads();
        gll16(Tbc + a1 + k0,      As + w * 1024);
        gll16(Tbc + a1 + k0 + 32, As + w * 1024 + 512);
        gll16(Tbc + a2 + k0,      As + (w + 4) * 1024);
        gll16(Tbc + a2 + k0 + 32, As + (w + 4) * 1024 + 512);
        gll16(Wtc + b1 + k0,      Bs + w * 1024);
        gll16(Wtc + b1 + k0 + 32, Bs + w * 1024 + 512);
        gll16(Wtc + b2 + k0,      Bs + (w + 4) * 1024);
        gll16(Wtc + b2 + k0 + 32, Bs + (w + 4) * 1024 + 512);
        __syncthreads();
        #pragma unroll
        for (int kk = 0; kk < 2; kk++) {
            bfx8 af[4], bf[4];
            #pragma unroll
            for (int i = 0; i < 4; i++) af[i] = *(const bfx8*)&As[(ga + i) * 1024 + kk * 512 + lane * 8];
            #pragma unroll
            for (int j = 0; j < 4; j++) bf[j] = *(const bfx8*)&Bs[(gb + j) * 1024 + kk * 512 + lane * 8];
            #pragma unroll
            for (int i = 0; i < 4; i++)
                #pragma unroll
                for (int j = 0; j < 4; j++)
                    acc[i][j] = __builtin_amdgcn_mfma_f32_16x16x32_bf16(af[i], bf[j], acc[i][j], 0, 0, 0);
        }
    }
    u16* Vb = V + (size_t)blockIdx.z * VHALF;
    #pragma unroll
    for (int j = 0; j < 4; j++) {
        int f = n0 + wn + j * 16 + (lane & 15);
        #pragma unroll
        for (int i = 0; i < 4; i++) {
            int rbase = m0 + wm + i * 16 + (lane >> 4) * 4;
            #pragma unroll
            for (int r = 0; r < 4; r++)
                Vb[(size_t)(rbase + r) * KW + f] = f2bf(0.25f * acc[i][j][r]);
        }
    }
}

// ---------------------------------------------------------------------------
__global__ __launch_bounds__(256) void gather_k(const u16* __restrict__ V,
                                                u16* __restrict__ yT, int n) {
    int idx = blockIdx.x * 256 + threadIdx.x;      // PIX*128
    int c = idx & 127, pix = idx >> 7;
    int yy = pix / HO, xx = pix - yy * HO;
    int ky0 = (yy + 1) & 1, kx0 = (xx + 1) & 1;
    float s = 0.0f;
    #pragma unroll
    for (int a = 0; a < 2; a++) {
        int ky = ky0 + a * 2;
        int py = yy + 1 - ky;
        if (py < 0 || py >= HO) continue;
        int pi = py >> 1;
        #pragma unroll
        for (int b = 0; b < 2; b++) {
            int kx = kx0 + b * 2;
            int px = xx + 1 - kx;
            if (px < 0 || px >= HO) continue;
            int pj = px >> 1;
            size_t off = (size_t)(pi * HS + pj) * KW + (ky * 4 + kx) * 128 + c;
            s += bf2f(V[off]) + bf2f(V[VHALF + off]) + bf2f(V[2 * VHALF + off]);
        }
    }
    yT[(size_t)(n * PIX + pix) * CCH + c] = f2bf(s);
}

// ---------------------------------------------------------------------------
__global__ __launch_bounds__(256) void wprep_k(const float* __restrict__ fw,
                                               u16* __restrict__ Wf) {
    int idx = blockIdx.x * 256 + threadIdx.x;
    int c = idx & 127;
    int tap = (idx >> 7) % 9;
    int go = idx / (128 * 9);
    Wf[idx] = f2bf(fw[((size_t)go * 128 + c) * 9 + tap]);
}

// ---------------------------------------------------------------------------
__global__ __launch_bounds__(256) void fuse_mfma_k(const u16* __restrict__ yT,
                                                   const u16* __restrict__ Wf,
                                                   const float* __restrict__ fb,
                                                   float* __restrict__ out) {
    int n = blockIdx.z, g = blockIdx.y;
    const int d = 1 << g;
    int tid = threadIdx.x, wv = tid >> 6, lane = tid & 63;
    int pix0 = blockIdx.x * 64 + wv * 16;
    int h = pix0 / HO, w0 = pix0 - h * HO;
    int m = lane & 15, q = lane >> 4;
    int oc = m;
    const u16* brow = Wf + ((size_t)(g * 16 + oc) * 9) * CCH + q * 8;
    f32x4 acc = (f32x4)0.0f;

    #pragma unroll
    for (int tap = 0; tap < 9; tap++) {
        int dy = (tap / 3 - 1) * d, dx = (tap % 3 - 1) * d;
        int hh = h + dy;
        int ww = w0 + m + dx;
        bool v = (hh >= 0) & (hh < HO) & (ww >= 0) & (ww < HO);
        const u16* arow = yT + ((size_t)(n * PIX + hh * HO + ww)) * CCH + q * 8;
        const u16* bt = brow + tap * CCH;
        #pragma unroll
        for (int c0 = 0; c0 < CCH; c0 += 32) {
            bfx8 af = (bfx8)0;
            if (v) af = *(const bfx8*)(arow + c0);
            bfx8 bf = *(const bfx8*)(bt + c0);
            acc = __builtin_amdgcn_mfma_f32_16x16x32_bf16(af, bf, acc, 0, 0, 0);
        }
    }
    float bias = fb[g * 16 + oc];
    f32x4 o;
    #pragma unroll
    for (int r = 0; r < 4; r++) o[r] = fmaxf(acc[r] + bias, 0.0f);
    size_t oi = ((size_t)(n * 64 + g * 16 + oc)) * PIX + pix0 + q * 4;
    *(f32x4*)&out[oi] = o;
}

// ---------------------------------------------------------------------------
extern "C" void kernel_launch(void* const* d_in, const int* in_sizes, int n_in,
                              void* d_out, int out_size, void* d_ws, size_t ws_size,
                              hipStream_t stream) {
    const float* x1       = (const float*)d_in[0];
    const float* x2       = (const float*)d_in[1];
    const float* mask     = (const float*)d_in[2];
    const float* mask_all = (const float*)d_in[3];
    const float* fw       = (const float*)d_in[4];
    const float* fb       = (const float*)d_in[5];
    float* out = (float*)d_out;
    char* wsb  = (char*)d_ws;

    u16*   Xh    = (u16*)(wsb + XTH_B);
    u16*   Xl    = (u16*)(wsb + XTL_B);
    float* pxn   = (float*)(wsb + PXN_B);
    float* rnorm = (float*)(wsb + NRM_B);
    float* mmb   = (float*)(wsb + MM_B);
    u16*   Wf    = (u16*)(wsb + WF_B);
    u16*   Wtc   = (u16*)(wsb + WT_B);
    float* S     = (float*)(wsb + S_B);
    u16*   Tbc   = (u16*)(wsb + TBD_B);    // aliases dead S
    u16*   V     = (u16*)(wsb + V_B);      // 3 thirds; overlaps dead Z (serially safe)
    float* Z     = (float*)(wsb + Z_B);
    u16*   yT    = (u16*)(wsb + YT_B);
    int*   cmap  = (int*)(wsb + CMAP_B);
    int*   lidx  = (int*)(wsb + LIDX_B);
    int*   meta  = (int*)(wsb + MET_B);

    wprep_k<<<(64 * 9 * 128) / 256, 256, 0, stream>>>(fw, Wf);
    xprep_k<<<dim3(LL / 32, 1, NB), 256, 0, stream>>>(x2, Xh, Xl, pxn);
    boxnorm_k<<<dim3(LL / 256, 1, NB), 256, 0, stream>>>(pxn, mask, rnorm, mmb);
    scan_k<<<NB, 256, 0, stream>>>(mmb, cmap, lidx, meta);

    for (int n = 0; n < NB; n++) {
        sgemm_k<<<171, 256, 0, stream>>>(Xh + (size_t)n * LL * CCH,
                                         Xl + (size_t)n * LL * CCH, S);
        zsum_k<<<HS * (HS + 1) / 2, 256, 0, stream>>>(S, Z);
        softmax_k<<<LL, 256, 0, stream>>>(Z, Tbc, rnorm, mmb, mask_all, cmap, meta, n);
        build_W_k<<<(KW * LL) / 256, 256, 0, stream>>>(x1, Wtc, lidx, meta, n);
        gemm2_k<<<dim3(18, 16, 3), 256, 0, stream>>>(Tbc, Wtc, V, meta, n);
        gather_k<<<(PIX * 128) / 256, 256, 0, stream>>>(V, yT, n);
    }
    fuse_mfma_k<<<dim3(PIX / 64, 4, NB), 256, 0, stream>>>(yT, Wf, fb, out);
}